// Round 11
// baseline (435.112 us; speedup 1.0000x reference)
//
#include <hip/hip_runtime.h>
#include <hip/hip_bf16.h>
#include <hip/hip_fp16.h>

#define NN 100000
#define EE 1600000
#define HIDD 128
#define GG 64
#define NB 512          // dst buckets
#define NPB 196         // nodes per bucket (511*196 >= NN)
#define NCH 391         // edge chunks
#define CH 4096         // edges per chunk

typedef short bf16x8 __attribute__((ext_vector_type(8)));
typedef float f32x4 __attribute__((ext_vector_type(4)));

// ---------------- bf16 helpers ----------------
__device__ inline unsigned int f2bf(float f) {
    unsigned int u = __float_as_uint(f);
    return (u + 0x7FFFu + ((u >> 16) & 1u)) >> 16;   // RNE, finite inputs
}
__device__ inline unsigned int pk2(float a, float b) { return f2bf(a) | (f2bf(b) << 16); }
__device__ inline float blo(unsigned int u) { return __uint_as_float(u << 16); }
__device__ inline float bhi(unsigned int u) { return __uint_as_float(u & 0xFFFF0000u); }

// ---------------- bucketed CSR build (no global per-edge atomics) ----------------

__global__ __launch_bounds__(256) void k_bhist(const int* __restrict__ ei,
                                               int* __restrict__ wg_hist) {
    __shared__ int cnt[NB];
    int t = threadIdx.x;
    cnt[t] = 0; cnt[t + 256] = 0;
    __syncthreads();
    int e0 = blockIdx.x * CH;
    #pragma unroll
    for (int i = 0; i < CH / 256; ++i) {
        int e = e0 + i * 256 + t;
        if (e < EE) {
            unsigned d = (unsigned)ei[EE + e];
            atomicAdd(&cnt[d / NPB], 1);
        }
    }
    __syncthreads();
    wg_hist[blockIdx.x * NB + t] = cnt[t];
    wg_hist[blockIdx.x * NB + 256 + t] = cnt[t + 256];
}

__global__ __launch_bounds__(512) void k_bscan_col(const int* __restrict__ wg_hist,
                                                   int* __restrict__ ofs,
                                                   int* __restrict__ btot) {
    __shared__ int sd[512];
    int b = blockIdx.x;
    int t = threadIdx.x;
    int v = (t < NCH) ? wg_hist[t * NB + b] : 0;
    sd[t] = v;
    __syncthreads();
    for (int off = 1; off < 512; off <<= 1) {
        int u = (t >= off) ? sd[t - off] : 0;
        __syncthreads();
        sd[t] += u;
        __syncthreads();
    }
    if (t < NCH) ofs[t * NB + b] = sd[t] - v;   // column-local exclusive
    if (t == 511) btot[b] = sd[511];
}

__global__ __launch_bounds__(512) void k_bbase(const int* __restrict__ btot,
                                               int* __restrict__ bbase) {
    __shared__ int sd[512];
    int t = threadIdx.x;
    int v = btot[t];
    sd[t] = v;
    __syncthreads();
    for (int off = 1; off < 512; off <<= 1) {
        int u = (t >= off) ? sd[t - off] : 0;
        __syncthreads();
        sd[t] += u;
        __syncthreads();
    }
    bbase[t] = sd[t] - v;
    if (t == 511) bbase[512] = sd[511];
}

__global__ __launch_bounds__(256) void k_bscatter(const int* __restrict__ ei,
                                                  const float* __restrict__ ea,
                                                  const int* __restrict__ ofs,
                                                  const int* __restrict__ bbase,
                                                  uint2* __restrict__ ebuf) {
    __shared__ int lcnt[NB];
    __shared__ int sofs[NB];
    int t = threadIdx.x;
    lcnt[t] = 0; lcnt[t + 256] = 0;
    sofs[t] = ofs[blockIdx.x * NB + t] + bbase[t];
    sofs[t + 256] = ofs[blockIdx.x * NB + 256 + t] + bbase[t + 256];
    __syncthreads();
    int e0 = blockIdx.x * CH;
    #pragma unroll
    for (int i = 0; i < CH / 256; ++i) {
        int e = e0 + i * 256 + t;
        if (e < EE) {
            unsigned s = (unsigned)ei[e];
            unsigned d = (unsigned)ei[EE + e];
            float w = ea[e];
            unsigned b = d / NPB;
            unsigned dloc = d - b * NPB;
            int r = atomicAdd(&lcnt[b], 1);
            ebuf[sofs[b] + r] = make_uint2(s | (dloc << 17), __float_as_uint(w));
        }
    }
}

__global__ __launch_bounds__(256) void k_bsort(const uint2* __restrict__ ebuf,
                                               const int* __restrict__ bbase,
                                               uint2* __restrict__ csr,
                                               int* __restrict__ src32,
                                               int* __restrict__ dst32,
                                               int* __restrict__ row_ptr) {
    __shared__ int cnt[NPB];
    __shared__ int sc[256];
    __shared__ int pos[NPB];
    int b = blockIdx.x;
    int t = threadIdx.x;
    int ebeg = bbase[b], eend = bbase[b + 1];
    int n0 = b * NPB;
    int nn = NN - n0; if (nn > NPB) nn = NPB;
    if (t < NPB) cnt[t] = 0;
    __syncthreads();
    for (int j = ebeg + t; j < eend; j += 256) {
        uint2 r = ebuf[j];
        atomicAdd(&cnt[r.x >> 17], 1);
    }
    __syncthreads();
    int v = (t < NPB) ? cnt[t] : 0;
    sc[t] = v;
    __syncthreads();
    for (int off = 1; off < 256; off <<= 1) {
        int u = (t >= off) ? sc[t - off] : 0;
        __syncthreads();
        sc[t] += u;
        __syncthreads();
    }
    int lofs = sc[t] - v; // exclusive
    if (t < NPB) {
        pos[t] = lofs;
        if (t < nn) row_ptr[n0 + t] = ebeg + lofs;
    }
    __syncthreads();
    for (int j = ebeg + t; j < eend; j += 256) {
        uint2 r = ebuf[j];
        int dloc = r.x >> 17;
        int slot = ebeg + atomicAdd(&pos[dloc], 1);
        int s = (int)(r.x & 0x1FFFFu);
        csr[slot] = make_uint2((unsigned)s, r.y);
        src32[slot] = s;
        dst32[slot] = n0 + dloc;
    }
    if (b == 0 && t == 0) row_ptr[NN] = EE;
}

// ---------------- derived constants ----------------
// cblk: 0..127 P | 128..255 Q | 256..511 bn_scale[l] | 512..767 bn_shift[l]
// 768 ps | 772 qs | 776 pd | 780 qd | 784+4l aeu[l] | 792+4l aev[l]

__global__ void k_derive(const float* __restrict__ enc_w, const float* __restrict__ enc_b,
                         const float* __restrict__ eenc_w, const float* __restrict__ eenc_b,
                         const float* __restrict__ lin_w, const float* __restrict__ lin_edge_w,
                         const float* __restrict__ att_src, const float* __restrict__ att_dst,
                         const float* __restrict__ att_edge,
                         const float* __restrict__ bn_gamma, const float* __restrict__ bn_beta,
                         const float* __restrict__ bn_mean, const float* __restrict__ bn_var,
                         float* __restrict__ cblk) {
    int t = threadIdx.x; // 128
    __shared__ float red[128];

    float P = 0.f, Q = 0.f;
    for (int j = 0; j < 128; ++j) {
        float w = lin_w[j * 128 + t];
        P += enc_w[j] * w;
        Q += enc_b[j] * w;
    }
    cblk[t] = P;
    cblk[128 + t] = Q;

    for (int l = 0; l < 2; ++l) {
        float sc = bn_gamma[l * 128 + t] * rsqrtf(bn_var[l * 128 + t] + 1e-5f);
        cblk[256 + l * 128 + t] = sc;
        cblk[512 + l * 128 + t] = bn_beta[l * 128 + t] - bn_mean[l * 128 + t] * sc;
    }

    auto headred = [&](float v, int outbase) {
        red[t] = v;
        __syncthreads();
        if (t < 4) {
            float s = 0.f;
            for (int c = 0; c < 32; ++c) s += red[t * 32 + c];
            cblk[outbase + t] = s;
        }
        __syncthreads();
    };

    headred(P * att_src[t], 768);
    headred(Q * att_src[t], 772);
    headred(P * att_dst[t], 776);
    headred(Q * att_dst[t], 780);

    for (int l = 0; l < 2; ++l) {
        float W1 = 0.f, W2 = 0.f;
        for (int j = 0; j < 128; ++j) {
            float w = lin_edge_w[l * 16384 + j * 128 + t];
            W1 += eenc_w[j] * w;
            W2 += eenc_b[j] * w;
        }
        headred(W1 * att_edge[l * 128 + t], 784 + l * 4);
        headred(W2 * att_edge[l * 128 + t], 792 + l * 4);
    }
}

// layer-1 weight transpose -> bf16 (LDS-staged, coalesced both sides)
__global__ __launch_bounds__(256) void k_wpk(const float* __restrict__ lin_w,
                                             unsigned short* __restrict__ wpk16) {
    __shared__ float s[128 * 129];
    int t = threadIdx.x;
    for (int i = t; i < 16384; i += 256) {
        int k = i >> 7, c = i & 127;
        s[k * 129 + c] = lin_w[16384 + i];
    }
    __syncthreads();
    for (int i = t; i < 16384; i += 256) {
        int c = i >> 7, k = i & 127;
        wpk16[i] = (unsigned short)f2bf(s[k * 129 + c]);
    }
}

// ---------------- layer 0: wave per node over CSR (no atomics) ----------------

__global__ __launch_bounds__(256) void k_l0(const uint2* __restrict__ csr,
                                            const int* __restrict__ row_ptr,
                                            const float* __restrict__ x,
                                            const float* __restrict__ cblk,
                                            float* __restrict__ tmp0) {
    int wid = threadIdx.x >> 6, lane = threadIdx.x & 63;
    int n = blockIdx.x * 4 + wid;
    if (n >= NN) return;
    int h = lane & 3, eo = lane >> 2;
    float xdv = x[n];
    float ps = cblk[768 + h], qs = cblk[772 + h];
    float base = xdv * cblk[776 + h] + cblk[780 + h] + cblk[792 + h];
    float au = cblk[784 + h];
    int jb = row_ptr[n], je = row_ptr[n + 1];
    float s = 0.f, sx = 0.f;
    for (int j0 = jb; j0 < je; j0 += 16) {
        int j = j0 + eo;
        if (j < je) {
            uint2 r = csr[j];
            float xsv = x[r.x];
            float w = __uint_as_float(r.y);
            float a = xsv * ps + qs + base + w * au;
            a = (a > 0.f) ? a : 0.2f * a;
            float p = __expf(a);
            s += p;
            sx += p * xsv;
        }
    }
    #pragma unroll
    for (int off = 4; off < 64; off <<= 1) {
        s += __shfl_xor(s, off, 64);
        sx += __shfl_xor(sx, off, 64);
    }
    if (lane < 4) {
        tmp0[(size_t)n * 8 + lane] = s;
        tmp0[(size_t)n * 8 + 4 + lane] = sx;
    }
}

__global__ void k_l0_epi(const float* __restrict__ x, const float* __restrict__ enc_w,
                         const float* __restrict__ enc_b, const float* __restrict__ conv_b,
                         const float* __restrict__ cblk, const float* __restrict__ tmp0,
                         unsigned short* __restrict__ h16) {
    int idx = blockIdx.x * blockDim.x + threadIdx.x;
    if (idx >= NN * HIDD) return;
    int n = idx >> 7, k = idx & 127, h = (k >> 5) & 3;
    float s = tmp0[n * 8 + h];
    float sx = tmp0[n * 8 + 4 + h];
    float inv = 1.f / (s + 1e-16f);
    float agg = (sx * cblk[k] + s * cblk[128 + k]) * inv + conv_b[k];
    float o = agg * cblk[256 + k] + cblk[512 + k];
    float hv = fmaxf(o, 0.f) + x[n] * enc_w[k] + enc_b[k];
    h16[idx] = (unsigned short)f2bf(hv);
}

// ---------------- layer 1 GEMM: MFMA bf16, LDS-staged packed stores ----------------

__global__ __launch_bounds__(256) void k_gemm_mfma(const unsigned short* __restrict__ h16,
                                                   const unsigned short* __restrict__ wpk,
                                                   unsigned short* __restrict__ xs16) {
    __shared__ unsigned short st[64 * 136];   // padded row stride (272 B = 17 * 16 B)
    int wid = threadIdx.x >> 6, lane = threadIdx.x & 63;
    int rbase = blockIdx.x * 64 + wid * 16;
    int rloc = wid * 16;
    int hi = lane >> 4, c15 = lane & 15;

    const bf16x8* hrow = (const bf16x8*)(h16 + (size_t)(rbase + c15) * 128);
    bf16x8 a0 = hrow[hi];
    bf16x8 a1 = hrow[4 + hi];
    bf16x8 a2 = hrow[8 + hi];
    bf16x8 a3 = hrow[12 + hi];

    f32x4 acc[8];
    #pragma unroll
    for (int t8 = 0; t8 < 8; ++t8) {
        const bf16x8* wrow = (const bf16x8*)(wpk + (size_t)(t8 * 16 + c15) * 128);
        f32x4 a_ = {0.f, 0.f, 0.f, 0.f};
        a_ = __builtin_amdgcn_mfma_f32_16x16x32_bf16(a0, wrow[hi], a_, 0, 0, 0);
        a_ = __builtin_amdgcn_mfma_f32_16x16x32_bf16(a1, wrow[4 + hi], a_, 0, 0, 0);
        a_ = __builtin_amdgcn_mfma_f32_16x16x32_bf16(a2, wrow[8 + hi], a_, 0, 0, 0);
        a_ = __builtin_amdgcn_mfma_f32_16x16x32_bf16(a3, wrow[12 + hi], a_, 0, 0, 0);
        acc[t8] = a_;
    }
    #pragma unroll
    for (int j = 0; j < 4; ++j) {
        int r = rloc + hi * 4 + j;
        #pragma unroll
        for (int t8 = 0; t8 < 8; ++t8) {
            st[r * 136 + t8 * 16 + c15] = (unsigned short)f2bf(acc[t8][j]);
        }
    }
    __syncthreads();
    uint4* g4 = (uint4*)(xs16 + (size_t)blockIdx.x * 64 * 128);
    int t = threadIdx.x;
    #pragma unroll
    for (int i = t; i < 1024; i += 256) {
        int r = i >> 4, cw = i & 15;
        g4[i] = *(const uint4*)(st + r * 136 + cw * 8);
    }
}

// a_s1 / a_d1: wave per node from bf16 xs
__global__ void k_asad(const unsigned short* __restrict__ xs16,
                       const float* __restrict__ att_src1, const float* __restrict__ att_dst1,
                       float* __restrict__ a_s, float* __restrict__ a_d) {
    int wid = threadIdx.x >> 6, lane = threadIdx.x & 63;
    int n = blockIdx.x * 4 + wid;
    if (n >= NN) return;
    unsigned int u = *(const unsigned int*)(xs16 + (size_t)n * 128 + lane * 2);
    float v0 = blo(u), v1 = bhi(u);
    float2 as2 = *(const float2*)(att_src1 + lane * 2);
    float2 ad2 = *(const float2*)(att_dst1 + lane * 2);
    float vs = v0 * as2.x + v1 * as2.y;
    float vd = v0 * ad2.x + v1 * ad2.y;
    #pragma unroll
    for (int off = 1; off < 16; off <<= 1) {
        vs += __shfl_xor(vs, off, 64);
        vd += __shfl_xor(vd, off, 64);
    }
    if ((lane & 15) == 0) {
        a_s[n * 4 + (lane >> 4)] = vs;
        a_d[n * 4 + (lane >> 4)] = vd;
    }
}

// ---------------- layer-1 edge p precompute: p8[e] = 4 x f16 ----------------

__global__ __launch_bounds__(256) void k_l1e(const uint2* __restrict__ csr,
                                             const int* __restrict__ dst32,
                                             const float* __restrict__ a_s,
                                             const float* __restrict__ a_d,
                                             const float* __restrict__ cblk,
                                             uint2* __restrict__ p8) {
    int e = blockIdx.x * blockDim.x + threadIdx.x;
    if (e >= EE) return;
    uint2 r = csr[e];
    int s = (int)r.x;
    int d = dst32[e];
    float w = __uint_as_float(r.y);
    float4 as4 = *(const float4*)(a_s + (size_t)s * 4);
    float4 ad4 = *(const float4*)(a_d + (size_t)d * 4);
    float av[4] = {as4.x + ad4.x, as4.y + ad4.y, as4.z + ad4.z, as4.w + ad4.w};
    unsigned short ph[4];
    #pragma unroll
    for (int h = 0; h < 4; ++h) {
        float a = av[h] + cblk[796 + h] + w * cblk[788 + h];
        a = (a > 0.f) ? a : 0.2f * a;
        float p = __expf(a);
        ph[h] = __half_as_ushort(__float2half(p));
    }
    p8[e] = make_uint2((unsigned)ph[0] | ((unsigned)ph[1] << 16),
                       (unsigned)ph[2] | ((unsigned)ph[3] << 16));
}

// ---------------- layer 1 aggregation: slim inner loop, 8x unrolled ----------------

__global__ __launch_bounds__(256) void k_l1_agg(const unsigned short* __restrict__ xs16,
                                                const int* __restrict__ src32,
                                                const uint2* __restrict__ p8,
                                                const int* __restrict__ row_ptr,
                                                const float* __restrict__ cblk,
                                                const float* __restrict__ conv_b,
                                                unsigned short* __restrict__ outb) {
    int wid = threadIdx.x >> 6, lane = threadIdx.x & 63;
    int n = blockIdx.x * 4 + wid;
    if (n >= NN) return;
    int h = lane >> 4;
    int c0 = lane * 2;
    int hw = (h >> 1) << 2;     // byte offset of dword holding this head's f16
    int hs = (h & 1) * 16;      // shift within dword

    float acc0 = 0.f, acc1 = 0.f, s = 0.f;
    int jb = row_ptr[n], je = row_ptr[n + 1];
    const char* xb = (const char*)xs16;
    const char* pb = (const char*)p8;
    int j = jb;
    for (; j + 7 < je; j += 8) {
        int sq[8];
        unsigned int up[8];
        unsigned int u[8];
        #pragma unroll
        for (int q = 0; q < 8; ++q) sq[q] = src32[j + q];
        #pragma unroll
        for (int q = 0; q < 8; ++q)
            up[q] = *(const unsigned int*)(pb + (size_t)(j + q) * 8 + hw);
        #pragma unroll
        for (int q = 0; q < 8; ++q)
            u[q] = *(const unsigned int*)(xb + ((size_t)sq[q] << 8) + (lane << 2));
        #pragma unroll
        for (int q = 0; q < 8; ++q) {
            float p = __half2float(__ushort_as_half((unsigned short)(up[q] >> hs)));
            s += p;
            acc0 += p * blo(u[q]);
            acc1 += p * bhi(u[q]);
        }
    }
    for (; j < je; ++j) {
        int sq = src32[j];
        unsigned int up = *(const unsigned int*)(pb + (size_t)j * 8 + hw);
        unsigned int u = *(const unsigned int*)(xb + ((size_t)sq << 8) + (lane << 2));
        float p = __half2float(__ushort_as_half((unsigned short)(up >> hs)));
        s += p;
        acc0 += p * blo(u);
        acc1 += p * bhi(u);
    }
    float inv = 1.f / (s + 1e-16f);
    float o0 = acc0 * inv + conv_b[128 + c0];
    float o1 = acc1 * inv + conv_b[128 + c0 + 1];
    o0 = o0 * cblk[384 + c0] + cblk[640 + c0];
    o1 = o1 * cblk[384 + c0 + 1] + cblk[640 + c0 + 1];
    unsigned int pk = pk2(fmaxf(o0, 0.f), fmaxf(o1, 0.f));
    *(unsigned int*)(outb + (size_t)n * 128 + c0) = pk;
}

// ---------------- pooling (h = h16 + outb), 32 nodes/block, ILP fast path ----------------

__global__ __launch_bounds__(128) void k_pool(const unsigned short* __restrict__ h16,
                                              const unsigned short* __restrict__ outb,
                                              const int* __restrict__ batch,
                                              float* __restrict__ pooled,
                                              float* __restrict__ gcnt) {
    int t = threadIdx.x;          // 128
    int c = (t & 63) * 2;         // channel pair
    int half = t >> 6;            // node parity
    int n0 = blockIdx.x * 32;     // NN = 3125*32 exactly
    int gfirst = batch[n0];
    int glast = batch[n0 + 31];
    if (gfirst == glast) {
        float a0 = 0.f, a1 = 0.f;
        #pragma unroll
        for (int i = 0; i < 16; ++i) {
            size_t n = (size_t)(n0 + half + i * 2);
            unsigned int uh = *(const unsigned int*)(h16 + n * 128 + c);
            unsigned int ub = *(const unsigned int*)(outb + n * 128 + c);
            a0 += blo(uh) + blo(ub);
            a1 += bhi(uh) + bhi(ub);
        }
        atomicAdd(&pooled[gfirst * 128 + c], a0);
        atomicAdd(&pooled[gfirst * 128 + c + 1], a1);
        if (t == 0) atomicAdd(&gcnt[gfirst], 32.f);
    } else if (half == 0) {
        float a0 = 0.f, a1 = 0.f;
        int run = 0;
        int gprev = gfirst;
        for (int n = n0; n < n0 + 32; ++n) {
            int g = batch[n];
            if (g != gprev) {
                atomicAdd(&pooled[gprev * 128 + c], a0);
                atomicAdd(&pooled[gprev * 128 + c + 1], a1);
                if (t == 0) atomicAdd(&gcnt[gprev], (float)run);
                a0 = a1 = 0.f;
                run = 0;
                gprev = g;
            }
            unsigned int uh = *(const unsigned int*)(h16 + (size_t)n * 128 + c);
            unsigned int ub = *(const unsigned int*)(outb + (size_t)n * 128 + c);
            a0 += blo(uh) + blo(ub);
            a1 += bhi(uh) + bhi(ub);
            run++;
        }
        atomicAdd(&pooled[gprev * 128 + c], a0);
        atomicAdd(&pooled[gprev * 128 + c + 1], a1);
        if (t == 0) atomicAdd(&gcnt[gprev], (float)run);
    }
}

__global__ void k_head(const float* __restrict__ pooled, const float* __restrict__ gcnt,
                       const float* __restrict__ w1, const float* __restrict__ b1,
                       const float* __restrict__ w2, const float* __restrict__ b2,
                       float* __restrict__ out) {
    int g = blockIdx.x;
    int j = threadIdx.x; // 64
    float inv = 1.f / fmaxf(gcnt[g], 1.f);
    float acc = b1[j];
    for (int k = 0; k < 128; ++k) acc += pooled[g * 128 + k] * inv * w1[k * 64 + j];
    float z = fmaxf(acc, 0.f);
    float v = z * w2[j];
    #pragma unroll
    for (int off = 32; off; off >>= 1) v += __shfl_down(v, off, 64);
    if (j == 0) out[g] = 1.f / (1.f + __expf(-(v + b2[0])));
}

// ---------------- launcher ----------------

extern "C" void kernel_launch(void* const* d_in, const int* in_sizes, int n_in,
                              void* d_out, int out_size, void* d_ws, size_t ws_size,
                              hipStream_t stream) {
    const float* x        = (const float*)d_in[0];
    const float* ea       = (const float*)d_in[1];
    const int*   ei       = (const int*)d_in[2];
    const int*   batch    = (const int*)d_in[3];
    const float* enc_w    = (const float*)d_in[4];
    const float* enc_b    = (const float*)d_in[5];
    const float* eenc_w   = (const float*)d_in[6];
    const float* eenc_b   = (const float*)d_in[7];
    const float* lin_w    = (const float*)d_in[8];
    const float* att_src  = (const float*)d_in[9];
    const float* att_dst  = (const float*)d_in[10];
    const float* att_edge = (const float*)d_in[11];
    const float* lin_edge = (const float*)d_in[12];
    const float* conv_b   = (const float*)d_in[13];
    const float* bn_gamma = (const float*)d_in[14];
    const float* bn_beta  = (const float*)d_in[15];
    const float* bn_mean  = (const float*)d_in[16];
    const float* bn_var   = (const float*)d_in[17];
    const float* w1       = (const float*)d_in[18];
    const float* b1       = (const float*)d_in[19];
    const float* w2       = (const float*)d_in[20];
    const float* b2       = (const float*)d_in[21];
    float* out = (float*)d_out;

    char* ws = (char*)d_ws;
    size_t off = 0;
    auto alloc = [&](size_t bytes) {
        size_t o = off;
        off = (off + bytes + 511) & ~(size_t)511;
        return o;
    };
    int*    wg_hist = (int*)(ws + alloc((size_t)NCH * NB * 4));
    int*    ofs     = (int*)(ws + alloc((size_t)NCH * NB * 4));
    int*    btot    = (int*)(ws + alloc(NB * 4));
    int*    bbase   = (int*)(ws + alloc((NB + 1) * 4));
    int*    row_ptr = (int*)(ws + alloc((size_t)(NN + 1) * 4));
    uint2*  ebuf    = (uint2*)(ws + alloc((size_t)EE * 8));   // dead after bsort -> reused as p8
    uint2*  csr     = (uint2*)(ws + alloc((size_t)EE * 8));
    int*    src32   = (int*)(ws + alloc((size_t)EE * 4));
    int*    dst32   = (int*)(ws + alloc((size_t)EE * 4));
    float*  cblk    = (float*)(ws + alloc(1024 * 4));
    unsigned short* wpk16 = (unsigned short*)(ws + alloc(128 * 128 * 2));
    float*  tmp0    = (float*)(ws + alloc((size_t)NN * 8 * 4));
    float*  a_s     = (float*)(ws + alloc((size_t)NN * 4 * 4));
    float*  a_d     = (float*)(ws + alloc((size_t)NN * 4 * 4));
    unsigned short* h16  = (unsigned short*)(ws + alloc((size_t)(NN + 64) * HIDD * 2));
    unsigned short* xs16 = (unsigned short*)(ws + alloc((size_t)(NN + 64) * HIDD * 2));
    unsigned short* outb = (unsigned short*)(ws + alloc((size_t)NN * HIDD * 2));
    float*  pooled  = (float*)(ws + alloc(GG * HIDD * 4 + GG * 4));
    float*  gcnt    = pooled + GG * HIDD;
    uint2*  p8      = ebuf;   // overlay: ebuf dead once bsort completes

    hipMemsetAsync(pooled, 0, GG * HIDD * 4 + GG * 4, stream);

    const int nwave4 = (NN + 3) / 4;      // 25000
    const int eblk   = (EE + 255) / 256;  // 6250

    k_bhist<<<NCH, 256, 0, stream>>>(ei, wg_hist);
    k_bscan_col<<<NB, 512, 0, stream>>>(wg_hist, ofs, btot);
    k_bbase<<<1, 512, 0, stream>>>(btot, bbase);
    k_bscatter<<<NCH, 256, 0, stream>>>(ei, ea, ofs, bbase, ebuf);
    k_bsort<<<511, 256, 0, stream>>>(ebuf, bbase, csr, src32, dst32, row_ptr);

    k_derive<<<1, 128, 0, stream>>>(enc_w, enc_b, eenc_w, eenc_b, lin_w, lin_edge,
                                    att_src, att_dst, att_edge,
                                    bn_gamma, bn_beta, bn_mean, bn_var, cblk);
    k_wpk<<<1, 256, 0, stream>>>(lin_w, wpk16);

    k_l0<<<nwave4, 256, 0, stream>>>(csr, row_ptr, x, cblk, tmp0);
    k_l0_epi<<<(NN * HIDD + 255) / 256, 256, 0, stream>>>(x, enc_w, enc_b, conv_b, cblk,
                                                          tmp0, h16);

    k_gemm_mfma<<<(NN + 63) / 64, 256, 0, stream>>>(h16, wpk16, xs16);
    k_asad<<<nwave4, 256, 0, stream>>>(xs16, att_src + 128, att_dst + 128, a_s, a_d);
    k_l1e<<<eblk, 256, 0, stream>>>(csr, dst32, a_s, a_d, cblk, p8);
    k_l1_agg<<<nwave4, 256, 0, stream>>>(xs16, src32, p8, row_ptr, cblk, conv_b, outb);

    k_pool<<<NN / 32, 128, 0, stream>>>(h16, outb, batch, pooled, gcnt);
    k_head<<<GG, 64, 0, stream>>>(pooled, gcnt, w1, b1, w2, b2, out);
}

// Round 12
// 386.415 us; speedup vs baseline: 1.1260x; 1.1260x over previous
//
#include <hip/hip_runtime.h>
#include <hip/hip_bf16.h>

#define NN 100000
#define EE 1600000
#define HIDD 128
#define GG 64
#define NB 512          // dst buckets
#define NPB 196         // nodes per bucket (511*196 >= NN)
#define NCH 391         // edge chunks
#define CH 4096         // edges per chunk

typedef short bf16x8 __attribute__((ext_vector_type(8)));
typedef float f32x4 __attribute__((ext_vector_type(4)));

// ---------------- bf16 helpers ----------------
__device__ inline unsigned int f2bf(float f) {
    unsigned int u = __float_as_uint(f);
    return (u + 0x7FFFu + ((u >> 16) & 1u)) >> 16;   // RNE, finite inputs
}
__device__ inline unsigned int pk2(float a, float b) { return f2bf(a) | (f2bf(b) << 16); }
__device__ inline float blo(unsigned int u) { return __uint_as_float(u << 16); }
__device__ inline float bhi(unsigned int u) { return __uint_as_float(u & 0xFFFF0000u); }

// ---------------- bucketed CSR build (no global per-edge atomics) ----------------

__global__ __launch_bounds__(256) void k_bhist(const int* __restrict__ ei,
                                               int* __restrict__ wg_hist) {
    __shared__ int cnt[NB];
    int t = threadIdx.x;
    cnt[t] = 0; cnt[t + 256] = 0;
    __syncthreads();
    int e0 = blockIdx.x * CH;
    #pragma unroll
    for (int i = 0; i < CH / 256; ++i) {
        int e = e0 + i * 256 + t;
        if (e < EE) {
            unsigned d = (unsigned)ei[EE + e];
            atomicAdd(&cnt[d / NPB], 1);
        }
    }
    __syncthreads();
    wg_hist[blockIdx.x * NB + t] = cnt[t];
    wg_hist[blockIdx.x * NB + 256 + t] = cnt[t + 256];
}

__global__ __launch_bounds__(512) void k_bscan_col(const int* __restrict__ wg_hist,
                                                   int* __restrict__ ofs,
                                                   int* __restrict__ btot) {
    __shared__ int sd[512];
    int b = blockIdx.x;
    int t = threadIdx.x;
    int v = (t < NCH) ? wg_hist[t * NB + b] : 0;
    sd[t] = v;
    __syncthreads();
    for (int off = 1; off < 512; off <<= 1) {
        int u = (t >= off) ? sd[t - off] : 0;
        __syncthreads();
        sd[t] += u;
        __syncthreads();
    }
    if (t < NCH) ofs[t * NB + b] = sd[t] - v;   // column-local exclusive
    if (t == 511) btot[b] = sd[511];
}

__global__ __launch_bounds__(512) void k_bbase(const int* __restrict__ btot,
                                               int* __restrict__ bbase) {
    __shared__ int sd[512];
    int t = threadIdx.x;
    int v = btot[t];
    sd[t] = v;
    __syncthreads();
    for (int off = 1; off < 512; off <<= 1) {
        int u = (t >= off) ? sd[t - off] : 0;
        __syncthreads();
        sd[t] += u;
        __syncthreads();
    }
    bbase[t] = sd[t] - v;
    if (t == 511) bbase[512] = sd[511];
}

__global__ __launch_bounds__(256) void k_bscatter(const int* __restrict__ ei,
                                                  const float* __restrict__ ea,
                                                  const int* __restrict__ ofs,
                                                  const int* __restrict__ bbase,
                                                  uint2* __restrict__ ebuf) {
    __shared__ int lcnt[NB];
    __shared__ int sofs[NB];
    int t = threadIdx.x;
    lcnt[t] = 0; lcnt[t + 256] = 0;
    sofs[t] = ofs[blockIdx.x * NB + t] + bbase[t];
    sofs[t + 256] = ofs[blockIdx.x * NB + 256 + t] + bbase[t + 256];
    __syncthreads();
    int e0 = blockIdx.x * CH;
    #pragma unroll
    for (int i = 0; i < CH / 256; ++i) {
        int e = e0 + i * 256 + t;
        if (e < EE) {
            unsigned s = (unsigned)ei[e];
            unsigned d = (unsigned)ei[EE + e];
            float w = ea[e];
            unsigned b = d / NPB;
            unsigned dloc = d - b * NPB;
            int r = atomicAdd(&lcnt[b], 1);
            ebuf[sofs[b] + r] = make_uint2(s | (dloc << 17), __float_as_uint(w));
        }
    }
}

__global__ __launch_bounds__(256) void k_bsort(const uint2* __restrict__ ebuf,
                                               const int* __restrict__ bbase,
                                               uint2* __restrict__ csr,
                                               int* __restrict__ row_ptr) {
    __shared__ int cnt[NPB];
    __shared__ int sc[256];
    __shared__ int pos[NPB];
    int b = blockIdx.x;
    int t = threadIdx.x;
    int ebeg = bbase[b], eend = bbase[b + 1];
    int n0 = b * NPB;
    int nn = NN - n0; if (nn > NPB) nn = NPB;
    if (t < NPB) cnt[t] = 0;
    __syncthreads();
    for (int j = ebeg + t; j < eend; j += 256) {
        uint2 r = ebuf[j];
        atomicAdd(&cnt[r.x >> 17], 1);
    }
    __syncthreads();
    int v = (t < NPB) ? cnt[t] : 0;
    sc[t] = v;
    __syncthreads();
    for (int off = 1; off < 256; off <<= 1) {
        int u = (t >= off) ? sc[t - off] : 0;
        __syncthreads();
        sc[t] += u;
        __syncthreads();
    }
    int lofs = sc[t] - v; // exclusive
    if (t < NPB) {
        pos[t] = lofs;
        if (t < nn) row_ptr[n0 + t] = ebeg + lofs;
    }
    __syncthreads();
    for (int j = ebeg + t; j < eend; j += 256) {
        uint2 r = ebuf[j];
        int dloc = r.x >> 17;
        int slot = ebeg + atomicAdd(&pos[dloc], 1);
        csr[slot] = make_uint2(r.x & 0x1FFFFu, r.y);
    }
    if (b == 0 && t == 0) row_ptr[NN] = EE;
}

// ---------------- derived constants ----------------
// cblk: 0..127 P | 128..255 Q | 256..511 bn_scale[l] | 512..767 bn_shift[l]
// 768 ps | 772 qs | 776 pd | 780 qd | 784+4l aeu[l] | 792+4l aev[l]

__global__ void k_derive(const float* __restrict__ enc_w, const float* __restrict__ enc_b,
                         const float* __restrict__ eenc_w, const float* __restrict__ eenc_b,
                         const float* __restrict__ lin_w, const float* __restrict__ lin_edge_w,
                         const float* __restrict__ att_src, const float* __restrict__ att_dst,
                         const float* __restrict__ att_edge,
                         const float* __restrict__ bn_gamma, const float* __restrict__ bn_beta,
                         const float* __restrict__ bn_mean, const float* __restrict__ bn_var,
                         float* __restrict__ cblk) {
    int t = threadIdx.x; // 128
    __shared__ float red[128];

    float P = 0.f, Q = 0.f;
    for (int j = 0; j < 128; ++j) {
        float w = lin_w[j * 128 + t];
        P += enc_w[j] * w;
        Q += enc_b[j] * w;
    }
    cblk[t] = P;
    cblk[128 + t] = Q;

    for (int l = 0; l < 2; ++l) {
        float sc = bn_gamma[l * 128 + t] * rsqrtf(bn_var[l * 128 + t] + 1e-5f);
        cblk[256 + l * 128 + t] = sc;
        cblk[512 + l * 128 + t] = bn_beta[l * 128 + t] - bn_mean[l * 128 + t] * sc;
    }

    auto headred = [&](float v, int outbase) {
        red[t] = v;
        __syncthreads();
        if (t < 4) {
            float s = 0.f;
            for (int c = 0; c < 32; ++c) s += red[t * 32 + c];
            cblk[outbase + t] = s;
        }
        __syncthreads();
    };

    headred(P * att_src[t], 768);
    headred(Q * att_src[t], 772);
    headred(P * att_dst[t], 776);
    headred(Q * att_dst[t], 780);

    for (int l = 0; l < 2; ++l) {
        float W1 = 0.f, W2 = 0.f;
        for (int j = 0; j < 128; ++j) {
            float w = lin_edge_w[l * 16384 + j * 128 + t];
            W1 += eenc_w[j] * w;
            W2 += eenc_b[j] * w;
        }
        headred(W1 * att_edge[l * 128 + t], 784 + l * 4);
        headred(W2 * att_edge[l * 128 + t], 792 + l * 4);
    }
}

// layer-1 weight transpose -> bf16 (LDS-staged, coalesced both sides)
__global__ __launch_bounds__(256) void k_wpk(const float* __restrict__ lin_w,
                                             unsigned short* __restrict__ wpk16) {
    __shared__ float s[128 * 129];
    int t = threadIdx.x;
    for (int i = t; i < 16384; i += 256) {
        int k = i >> 7, c = i & 127;
        s[k * 129 + c] = lin_w[16384 + i];
    }
    __syncthreads();
    for (int i = t; i < 16384; i += 256) {
        int c = i >> 7, k = i & 127;
        wpk16[i] = (unsigned short)f2bf(s[k * 129 + c]);
    }
}

// ---------------- layer 0: wave per node over CSR (no atomics) ----------------

__global__ __launch_bounds__(256) void k_l0(const uint2* __restrict__ csr,
                                            const int* __restrict__ row_ptr,
                                            const float* __restrict__ x,
                                            const float* __restrict__ cblk,
                                            float* __restrict__ tmp0) {
    int wid = threadIdx.x >> 6, lane = threadIdx.x & 63;
    int n = blockIdx.x * 4 + wid;
    if (n >= NN) return;
    int h = lane & 3, eo = lane >> 2;
    float xdv = x[n];
    float ps = cblk[768 + h], qs = cblk[772 + h];
    float base = xdv * cblk[776 + h] + cblk[780 + h] + cblk[792 + h];
    float au = cblk[784 + h];
    int jb = row_ptr[n], je = row_ptr[n + 1];
    float s = 0.f, sx = 0.f;
    for (int j0 = jb; j0 < je; j0 += 16) {
        int j = j0 + eo;
        if (j < je) {
            uint2 r = csr[j];
            float xsv = x[r.x];
            float w = __uint_as_float(r.y);
            float a = xsv * ps + qs + base + w * au;
            a = (a > 0.f) ? a : 0.2f * a;
            float p = __expf(a);
            s += p;
            sx += p * xsv;
        }
    }
    #pragma unroll
    for (int off = 4; off < 64; off <<= 1) {
        s += __shfl_xor(s, off, 64);
        sx += __shfl_xor(sx, off, 64);
    }
    if (lane < 4) {
        tmp0[(size_t)n * 8 + lane] = s;
        tmp0[(size_t)n * 8 + 4 + lane] = sx;
    }
}

__global__ void k_l0_epi(const float* __restrict__ x, const float* __restrict__ enc_w,
                         const float* __restrict__ enc_b, const float* __restrict__ conv_b,
                         const float* __restrict__ cblk, const float* __restrict__ tmp0,
                         unsigned short* __restrict__ h16) {
    int idx = blockIdx.x * blockDim.x + threadIdx.x;
    if (idx >= NN * HIDD) return;
    int n = idx >> 7, k = idx & 127, h = (k >> 5) & 3;
    float s = tmp0[n * 8 + h];
    float sx = tmp0[n * 8 + 4 + h];
    float inv = 1.f / (s + 1e-16f);
    float agg = (sx * cblk[k] + s * cblk[128 + k]) * inv + conv_b[k];
    float o = agg * cblk[256 + k] + cblk[512 + k];
    float hv = fmaxf(o, 0.f) + x[n] * enc_w[k] + enc_b[k];
    h16[idx] = (unsigned short)f2bf(hv);
}

// ---------------- layer 1 GEMM: MFMA bf16, LDS-staged stores, fused a_s/a_d ----------------
// D mapping: within tile t8, col = t8*16 + (lane&15), row = rbase + (lane>>4)*4 + j.

__global__ __launch_bounds__(256) void k_gemm_mfma(const unsigned short* __restrict__ h16,
                                                   const unsigned short* __restrict__ wpk,
                                                   const float* __restrict__ att_src1,
                                                   const float* __restrict__ att_dst1,
                                                   unsigned short* __restrict__ xs16,
                                                   float* __restrict__ a_s,
                                                   float* __restrict__ a_d) {
    __shared__ unsigned short st[64 * 136];   // padded row stride
    int wid = threadIdx.x >> 6, lane = threadIdx.x & 63;
    int rbase = blockIdx.x * 64 + wid * 16;
    int rloc = wid * 16;
    int hi = lane >> 4, c15 = lane & 15;

    const bf16x8* hrow = (const bf16x8*)(h16 + (size_t)(rbase + c15) * 128);
    bf16x8 a0 = hrow[hi];
    bf16x8 a1 = hrow[4 + hi];
    bf16x8 a2 = hrow[8 + hi];
    bf16x8 a3 = hrow[12 + hi];

    f32x4 acc[8];
    #pragma unroll
    for (int t8 = 0; t8 < 8; ++t8) {
        const bf16x8* wrow = (const bf16x8*)(wpk + (size_t)(t8 * 16 + c15) * 128);
        f32x4 a_ = {0.f, 0.f, 0.f, 0.f};
        a_ = __builtin_amdgcn_mfma_f32_16x16x32_bf16(a0, wrow[hi], a_, 0, 0, 0);
        a_ = __builtin_amdgcn_mfma_f32_16x16x32_bf16(a1, wrow[4 + hi], a_, 0, 0, 0);
        a_ = __builtin_amdgcn_mfma_f32_16x16x32_bf16(a2, wrow[8 + hi], a_, 0, 0, 0);
        a_ = __builtin_amdgcn_mfma_f32_16x16x32_bf16(a3, wrow[12 + hi], a_, 0, 0, 0);
        acc[t8] = a_;
    }

    // fused a_s/a_d: lane's column in tile t8 is t8*16+c15
    float asw[8], adw[8];
    #pragma unroll
    for (int t8 = 0; t8 < 8; ++t8) {
        asw[t8] = att_src1[t8 * 16 + c15];
        adw[t8] = att_dst1[t8 * 16 + c15];
    }
    #pragma unroll
    for (int j = 0; j < 4; ++j) {
        float vs[4], vd[4];
        #pragma unroll
        for (int h = 0; h < 4; ++h) {
            vs[h] = acc[2 * h][j] * asw[2 * h] + acc[2 * h + 1][j] * asw[2 * h + 1];
            vd[h] = acc[2 * h][j] * adw[2 * h] + acc[2 * h + 1][j] * adw[2 * h + 1];
        }
        #pragma unroll
        for (int off = 1; off < 16; off <<= 1) {
            #pragma unroll
            for (int h = 0; h < 4; ++h) {
                vs[h] += __shfl_xor(vs[h], off, 64);
                vd[h] += __shfl_xor(vd[h], off, 64);
            }
        }
        if (c15 == 0) {
            size_t r = (size_t)(rbase + hi * 4 + j) * 4;
            *(float4*)(a_s + r) = make_float4(vs[0], vs[1], vs[2], vs[3]);
            *(float4*)(a_d + r) = make_float4(vd[0], vd[1], vd[2], vd[3]);
        }
    }

    #pragma unroll
    for (int j = 0; j < 4; ++j) {
        int r = rloc + hi * 4 + j;
        #pragma unroll
        for (int t8 = 0; t8 < 8; ++t8) {
            st[r * 136 + t8 * 16 + c15] = (unsigned short)f2bf(acc[t8][j]);
        }
    }
    __syncthreads();
    uint4* g4 = (uint4*)(xs16 + (size_t)blockIdx.x * 64 * 128);
    int t = threadIdx.x;
    #pragma unroll
    for (int i = t; i < 1024; i += 256) {
        int r = i >> 4, cw = i & 15;
        g4[i] = *(const uint4*)(st + r * 136 + cw * 8);
    }
}

// ---------------- layer 1 aggregation: wave per node, 8x unrolled (R10 form) ----------------

__global__ __launch_bounds__(256) void k_l1_agg(const unsigned short* __restrict__ xs16,
                                                const uint2* __restrict__ csr,
                                                const float* __restrict__ a_s,
                                                const float* __restrict__ a_d,
                                                const int* __restrict__ row_ptr,
                                                const float* __restrict__ cblk,
                                                const float* __restrict__ conv_b,
                                                unsigned short* __restrict__ outb) {
    int wid = threadIdx.x >> 6, lane = threadIdx.x & 63;
    int n = blockIdx.x * 4 + wid;
    if (n >= NN) return;
    int h = lane >> 4;
    int c0 = lane * 2;

    float adh = a_d[(size_t)n * 4 + h] + cblk[796 + h];  // + aev1
    float au = cblk[788 + h];                            // aeu1

    float acc0 = 0.f, acc1 = 0.f, s = 0.f;
    int jb = row_ptr[n], je = row_ptr[n + 1];
    const char* xb = (const char*)xs16;
    int j = jb;
    for (; j + 7 < je; j += 8) {
        uint2 r[8];
        float as[8];
        unsigned int u[8];
        #pragma unroll
        for (int q = 0; q < 8; ++q) r[q] = csr[j + q];
        #pragma unroll
        for (int q = 0; q < 8; ++q) as[q] = a_s[(size_t)r[q].x * 4 + h];
        #pragma unroll
        for (int q = 0; q < 8; ++q)
            u[q] = *(const unsigned int*)(xb + ((size_t)r[q].x << 8) + (lane << 2));
        #pragma unroll
        for (int q = 0; q < 8; ++q) {
            float al = as[q] + adh + __uint_as_float(r[q].y) * au;
            al = (al > 0.f) ? al : 0.2f * al;
            float p = __expf(al);
            s += p;
            acc0 += p * blo(u[q]);
            acc1 += p * bhi(u[q]);
        }
    }
    for (; j + 3 < je; j += 4) {
        uint2 r[4];
        float as[4];
        unsigned int u[4];
        #pragma unroll
        for (int q = 0; q < 4; ++q) r[q] = csr[j + q];
        #pragma unroll
        for (int q = 0; q < 4; ++q) as[q] = a_s[(size_t)r[q].x * 4 + h];
        #pragma unroll
        for (int q = 0; q < 4; ++q)
            u[q] = *(const unsigned int*)(xb + ((size_t)r[q].x << 8) + (lane << 2));
        #pragma unroll
        for (int q = 0; q < 4; ++q) {
            float al = as[q] + adh + __uint_as_float(r[q].y) * au;
            al = (al > 0.f) ? al : 0.2f * al;
            float p = __expf(al);
            s += p;
            acc0 += p * blo(u[q]);
            acc1 += p * bhi(u[q]);
        }
    }
    for (; j < je; ++j) {
        uint2 r0 = csr[j];
        float as0 = a_s[(size_t)r0.x * 4 + h];
        unsigned int u0 = *(const unsigned int*)(xb + ((size_t)r0.x << 8) + (lane << 2));
        float al0 = as0 + adh + __uint_as_float(r0.y) * au;
        al0 = (al0 > 0.f) ? al0 : 0.2f * al0;
        float p0 = __expf(al0);
        s += p0;
        acc0 += p0 * blo(u0);
        acc1 += p0 * bhi(u0);
    }
    float inv = 1.f / (s + 1e-16f);
    float o0 = acc0 * inv + conv_b[128 + c0];
    float o1 = acc1 * inv + conv_b[128 + c0 + 1];
    o0 = o0 * cblk[384 + c0] + cblk[640 + c0];
    o1 = o1 * cblk[384 + c0 + 1] + cblk[640 + c0 + 1];
    unsigned int pk = pk2(fmaxf(o0, 0.f), fmaxf(o1, 0.f));
    *(unsigned int*)(outb + (size_t)n * 128 + c0) = pk;
}

// ---------------- pooling (h = h16 + outb), 32 nodes/block, ILP fast path ----------------

__global__ __launch_bounds__(128) void k_pool(const unsigned short* __restrict__ h16,
                                              const unsigned short* __restrict__ outb,
                                              const int* __restrict__ batch,
                                              float* __restrict__ pooled,
                                              float* __restrict__ gcnt) {
    int t = threadIdx.x;          // 128
    int c = (t & 63) * 2;         // channel pair
    int half = t >> 6;            // node parity
    int n0 = blockIdx.x * 32;     // NN = 3125*32 exactly
    int gfirst = batch[n0];
    int glast = batch[n0 + 31];
    if (gfirst == glast) {
        float a0 = 0.f, a1 = 0.f;
        #pragma unroll
        for (int i = 0; i < 16; ++i) {
            size_t n = (size_t)(n0 + half + i * 2);
            unsigned int uh = *(const unsigned int*)(h16 + n * 128 + c);
            unsigned int ub = *(const unsigned int*)(outb + n * 128 + c);
            a0 += blo(uh) + blo(ub);
            a1 += bhi(uh) + bhi(ub);
        }
        atomicAdd(&pooled[gfirst * 128 + c], a0);
        atomicAdd(&pooled[gfirst * 128 + c + 1], a1);
        if (t == 0) atomicAdd(&gcnt[gfirst], 32.f);
    } else if (half == 0) {
        float a0 = 0.f, a1 = 0.f;
        int run = 0;
        int gprev = gfirst;
        for (int n = n0; n < n0 + 32; ++n) {
            int g = batch[n];
            if (g != gprev) {
                atomicAdd(&pooled[gprev * 128 + c], a0);
                atomicAdd(&pooled[gprev * 128 + c + 1], a1);
                if (t == 0) atomicAdd(&gcnt[gprev], (float)run);
                a0 = a1 = 0.f;
                run = 0;
                gprev = g;
            }
            unsigned int uh = *(const unsigned int*)(h16 + (size_t)n * 128 + c);
            unsigned int ub = *(const unsigned int*)(outb + (size_t)n * 128 + c);
            a0 += blo(uh) + blo(ub);
            a1 += bhi(uh) + bhi(ub);
            run++;
        }
        atomicAdd(&pooled[gprev * 128 + c], a0);
        atomicAdd(&pooled[gprev * 128 + c + 1], a1);
        if (t == 0) atomicAdd(&gcnt[gprev], (float)run);
    }
}

__global__ void k_head(const float* __restrict__ pooled, const float* __restrict__ gcnt,
                       const float* __restrict__ w1, const float* __restrict__ b1,
                       const float* __restrict__ w2, const float* __restrict__ b2,
                       float* __restrict__ out) {
    int g = blockIdx.x;
    int j = threadIdx.x; // 64
    float inv = 1.f / fmaxf(gcnt[g], 1.f);
    float acc = b1[j];
    for (int k = 0; k < 128; ++k) acc += pooled[g * 128 + k] * inv * w1[k * 64 + j];
    float z = fmaxf(acc, 0.f);
    float v = z * w2[j];
    #pragma unroll
    for (int off = 32; off; off >>= 1) v += __shfl_down(v, off, 64);
    if (j == 0) out[g] = 1.f / (1.f + __expf(-(v + b2[0])));
}

// ---------------- launcher ----------------

extern "C" void kernel_launch(void* const* d_in, const int* in_sizes, int n_in,
                              void* d_out, int out_size, void* d_ws, size_t ws_size,
                              hipStream_t stream) {
    const float* x        = (const float*)d_in[0];
    const float* ea       = (const float*)d_in[1];
    const int*   ei       = (const int*)d_in[2];
    const int*   batch    = (const int*)d_in[3];
    const float* enc_w    = (const float*)d_in[4];
    const float* enc_b    = (const float*)d_in[5];
    const float* eenc_w   = (const float*)d_in[6];
    const float* eenc_b   = (const float*)d_in[7];
    const float* lin_w    = (const float*)d_in[8];
    const float* att_src  = (const float*)d_in[9];
    const float* att_dst  = (const float*)d_in[10];
    const float* att_edge = (const float*)d_in[11];
    const float* lin_edge = (const float*)d_in[12];
    const float* conv_b   = (const float*)d_in[13];
    const float* bn_gamma = (const float*)d_in[14];
    const float* bn_beta  = (const float*)d_in[15];
    const float* bn_mean  = (const float*)d_in[16];
    const float* bn_var   = (const float*)d_in[17];
    const float* w1       = (const float*)d_in[18];
    const float* b1       = (const float*)d_in[19];
    const float* w2       = (const float*)d_in[20];
    const float* b2       = (const float*)d_in[21];
    float* out = (float*)d_out;

    char* ws = (char*)d_ws;
    size_t off = 0;
    auto alloc = [&](size_t bytes) {
        size_t o = off;
        off = (off + bytes + 511) & ~(size_t)511;
        return o;
    };
    int*    wg_hist = (int*)(ws + alloc((size_t)NCH * NB * 4));
    int*    ofs     = (int*)(ws + alloc((size_t)NCH * NB * 4));
    int*    btot    = (int*)(ws + alloc(NB * 4));
    int*    bbase   = (int*)(ws + alloc((NB + 1) * 4));
    int*    row_ptr = (int*)(ws + alloc((size_t)(NN + 1) * 4));
    uint2*  ebuf    = (uint2*)(ws + alloc((size_t)EE * 8));
    uint2*  csr     = (uint2*)(ws + alloc((size_t)EE * 8));
    float*  cblk    = (float*)(ws + alloc(1024 * 4));
    unsigned short* wpk16 = (unsigned short*)(ws + alloc(128 * 128 * 2));
    float*  tmp0    = (float*)(ws + alloc((size_t)NN * 8 * 4));
    float*  a_s     = (float*)(ws + alloc((size_t)(NN + 64) * 4 * 4));
    float*  a_d     = (float*)(ws + alloc((size_t)(NN + 64) * 4 * 4));
    unsigned short* h16  = (unsigned short*)(ws + alloc((size_t)(NN + 64) * HIDD * 2));
    unsigned short* xs16 = (unsigned short*)(ws + alloc((size_t)(NN + 64) * HIDD * 2));
    unsigned short* outb = (unsigned short*)(ws + alloc((size_t)NN * HIDD * 2));
    float*  pooled  = (float*)(ws + alloc(GG * HIDD * 4 + GG * 4));
    float*  gcnt    = pooled + GG * HIDD;

    hipMemsetAsync(pooled, 0, GG * HIDD * 4 + GG * 4, stream);

    const int nwave4 = (NN + 3) / 4;      // 25000

    k_bhist<<<NCH, 256, 0, stream>>>(ei, wg_hist);
    k_bscan_col<<<NB, 512, 0, stream>>>(wg_hist, ofs, btot);
    k_bbase<<<1, 512, 0, stream>>>(btot, bbase);
    k_bscatter<<<NCH, 256, 0, stream>>>(ei, ea, ofs, bbase, ebuf);
    k_bsort<<<511, 256, 0, stream>>>(ebuf, bbase, csr, row_ptr);

    k_derive<<<1, 128, 0, stream>>>(enc_w, enc_b, eenc_w, eenc_b, lin_w, lin_edge,
                                    att_src, att_dst, att_edge,
                                    bn_gamma, bn_beta, bn_mean, bn_var, cblk);
    k_wpk<<<1, 256, 0, stream>>>(lin_w, wpk16);

    k_l0<<<nwave4, 256, 0, stream>>>(csr, row_ptr, x, cblk, tmp0);
    k_l0_epi<<<(NN * HIDD + 255) / 256, 256, 0, stream>>>(x, enc_w, enc_b, conv_b, cblk,
                                                          tmp0, h16);

    k_gemm_mfma<<<(NN + 63) / 64, 256, 0, stream>>>(h16, wpk16, att_src + 128, att_dst + 128,
                                                    xs16, a_s, a_d);
    k_l1_agg<<<nwave4, 256, 0, stream>>>(xs16, csr, a_s, a_d, row_ptr, cblk, conv_b, outb);

    k_pool<<<NN / 32, 128, 0, stream>>>(h16, outb, batch, pooled, gcnt);
    k_head<<<GG, 64, 0, stream>>>(pooled, gcnt, w1, b1, w2, b2, out);
}